// Round 15
// baseline (363.279 us; speedup 1.0000x reference)
//
#include <hip/hip_runtime.h>
#include <hip/hip_bf16.h>

// Problem constants (B=2, D=64, H=W=96)
constexpr int B_    = 2;
constexpr int N_    = 9216;      // 96*96
constexpr int ITERS = 4;

constexpr int MTQ     = 128;          // queries per workgroup (m-split: 32/wave)
constexpr int MBF     = N_ / MTQ;     // 72 m-blocks
constexpr int KS      = 3;            // key-split factor
constexpr int KEYS_WG = N_ / KS;      // 3072 keys per workgroup
constexpr int KT      = 128;          // keys per staged tile (flash_kernel)
constexpr int KTILES  = KEYS_WG / KT; // 24 tiles
constexpr int KTF     = 32;           // keys per wave-private tile (flash_free)
constexpr int NTF     = KEYS_WG / KTF;// 96 wave-private tiles
constexpr int NWG     = B_ * MBF * KS;// 432 flash workgroups — all <= cap 2/CU
constexpr int PB2     = 288;          // prep n-blocks of 32
constexpr int CGRID   = B_ * (N_ / 32) * 2; // 1152 combine workgroups

constexpr float STEP = 0.5f;
constexpr float C2   = 0.43280851226668905f;  // KBW * log2(e)

using short8   = __attribute__((ext_vector_type(8))) short;
using float16v = __attribute__((ext_vector_type(16))) float;
typedef __attribute__((ext_vector_type(2))) __bf16 bf16x2;

__device__ __forceinline__ unsigned short f2bf(float f) {
  union { float f; unsigned u; } v; v.f = f;
  unsigned u = v.u;
  unsigned r = (u + 0x7fffu + ((u >> 16) & 1u)) >> 16;   // RNE
  return (unsigned short)r;
}

#if __has_builtin(__builtin_amdgcn_cvt_pk_bf16_f32)
__device__ __forceinline__ unsigned pk2bf(float a, float b) {
  bf16x2 r = __builtin_amdgcn_cvt_pk_bf16_f32(a, b);   // low <- a, high <- b, RNE
  union { bf16x2 h; unsigned u; } v; v.h = r; return v.u;
}
#else
__device__ __forceinline__ unsigned pk2bf(float a, float b) {
  return (unsigned)f2bf(a) | ((unsigned)f2bf(b) << 16);
}
#endif

// cs += lo(u) + hi(u) where u is a packed bf16 pair — 1 instr via dot2.
__device__ __forceinline__ float csum2(unsigned u, float cs) {
#if __has_builtin(__builtin_amdgcn_fdot2_f32_bf16)
  union { unsigned x; bf16x2 h; } a, o;
  a.x = u; o.x = 0x3f803f80u;                          // (1.0, 1.0) bf16
  return __builtin_amdgcn_fdot2_f32_bf16(a.h, o.h, cs, false);
#else
  union { unsigned u; float f; } lo, hi;
  lo.u = u << 16; hi.u = u & 0xffff0000u;
  return cs + lo.f + hi.f;
#endif
}

// Async global->LDS DMA, 16 B/lane; lds_base wave-uniform, lane i -> base+16i.
__device__ __forceinline__ void dma16(const unsigned short* g,
                                      unsigned short* lds_base, int lane) {
#if __has_builtin(__builtin_amdgcn_global_load_lds)
  __builtin_amdgcn_global_load_lds(
      (const __attribute__((address_space(1))) unsigned int*)g,
      (__attribute__((address_space(3))) unsigned int*)lds_base, 16, 0, 0);
#else
  *(int4*)((char*)lds_base + lane * 16) = *(const int4*)g;
#endif
}

// ---------------------------------------------------------------------------
// prep v2 (R19, kept): 576 blocks, float2 loads, packed bf16 stores.
// ---------------------------------------------------------------------------
__global__ void prep_kernel(const float* __restrict__ xin, float* __restrict__ out,
                            unsigned short* __restrict__ XT,
                            unsigned short* __restrict__ Xbf)
{
  const int bx = blockIdx.x;
  const int nb = bx % PB2, b = bx / PB2;
  const int n0 = nb * 32;
  const int tid = threadIdx.x;
  __shared__ float tile[64 * 33];

  #pragma unroll
  for (int r = 0; r < 4; ++r) {
    int idx = r * 256 + tid;                 // 0..1023 = 64 d x 16 j-pairs
    int d = idx >> 4, j2 = (idx & 15) * 2;
    size_t gsrc = ((size_t)b * 64 + d) * N_ + n0 + j2;
    float2 v = *(const float2*)(xin + gsrc);
    *(float2*)(out + (((size_t)b * 5 + 0) * 64 + d) * N_ + n0 + j2) = v;
    *(unsigned*)(Xbf + gsrc) = pk2bf(v.x, v.y);
    tile[d * 33 + j2]     = v.x;
    tile[d * 33 + j2 + 1] = v.y;
  }
  __syncthreads();

  #pragma unroll
  for (int r = 0; r < 4; ++r) {
    int idx = r * 256 + tid;                 // 0..1023 = 32 n x 32 d-pairs
    int nl = idx >> 5, d2 = (idx & 31) * 2;
    *(unsigned*)(XT + ((size_t)b * N_ + n0 + nl) * 64 + d2)
        = pk2bf(tile[d2 * 33 + nl], tile[(d2 + 1) * 33 + nl]);
  }
}

// ---------------------------------------------------------------------------
// flash (R17 config, FROZEN CONTROL — 72.6-75.0 µs across R17-R19 runs).
// ---------------------------------------------------------------------------
__global__ void __launch_bounds__(256, 2) flash_kernel(
    const unsigned short* __restrict__ XT,
    const unsigned short* __restrict__ Xbf,
    float* __restrict__ pacc, float* __restrict__ pcs)
{
  const int bx   = blockIdx.x;
  const int ks   = bx % KS;
  const int mb   = (bx / KS) % MBF;
  const int b    = bx / (MBF * KS);
  const int tid  = threadIdx.x;
  const int wave = tid >> 6, lane = tid & 63;
  const int c = lane & 31, h = lane >> 5;
  const int cp = (c & 0x13) | ((c & 4) << 1) | ((c & 8) >> 1);  // swap bits 2,3
  const int m0 = mb * MTQ;
  const int bpaddr = (lane ^ 32) << 2;

  const unsigned short* XTb = XT  + (size_t)b * N_ * 64;
  const unsigned short* Xb  = Xbf + (size_t)b * 64 * N_;

  __shared__ __align__(16) unsigned short sXT[2][KT * 64];   // [key][d] 16KiB x2
  __shared__ __align__(16) unsigned short sXB[2][64 * KT];   // [d][n]   16KiB x2

  const int rr  = lane >> 3, sc = lane & 7;
  const int gcT = sc ^ rr;
  const int rr4 = lane >> 4, sc16 = lane & 15;
  const int gcB0 = sc16 ^ rr4;                  // j even
  const int gcB1 = sc16 ^ (4 + rr4);            // j odd

  const int n0g0 = ks * KEYS_WG;

  const unsigned short* xtp  = XTb + (size_t)(n0g0 + wave * 32 + rr) * 64 + gcT * 8;
  const unsigned short* xbpA = Xb  + (size_t)(wave * 16 + rr4) * N_ + n0g0 + gcB0 * 8;
  const unsigned short* xbpB = Xb  + (size_t)(wave * 16 + rr4) * N_ + n0g0 + gcB1 * 8;

  auto stage = [&](int buf, const unsigned short* xt_,
                   const unsigned short* xbA_, const unsigned short* xbB_) {
    unsigned short* lt = &sXT[buf][wave * 32 * 64];
    unsigned short* lb = &sXB[buf][wave * 16 * 128];
    dma16(xt_,        lt,        lane);
    dma16(xt_ +  512, lt +  512, lane);
    dma16(xt_ + 1024, lt + 1024, lane);
    dma16(xt_ + 1536, lt + 1536, lane);
    dma16(xbA_,                    lb,        lane);
    dma16(xbB_ + (size_t) 4 * N_,  lb +  512, lane);
    dma16(xbA_ + (size_t) 8 * N_,  lb + 1024, lane);
    dma16(xbB_ + (size_t)12 * N_,  lb + 1536, lane);
  };

  stage(0, xtp, xbpA, xbpB);
  xtp += KT * 64; xbpA += KT; xbpB += KT;

  short8 qf[4];
  #pragma unroll
  for (int k = 0; k < 4; ++k) {
    short8 raw = *(const short8*)(XTb +
        (size_t)(m0 + wave * 32 + c) * 64 + k * 16 + h * 8);
    unsigned o[4];
    const unsigned* rw = (const unsigned*)&raw;
    #pragma unroll
    for (int p4 = 0; p4 < 4; ++p4) {
      union { unsigned u; float f; } lo, hi;
      lo.u = rw[p4] << 16; hi.u = rw[p4] & 0xffff0000u;
      o[p4] = pk2bf(lo.f * C2, hi.f * C2);
    }
    qf[k] = *(const short8*)o;
  }

  const int e = cp & 7;
  const unsigned short* afb[4];
  #pragma unroll
  for (int k = 0; k < 4; ++k)
    afb[k] = &sXT[0][cp * 64 + ((2 * k + h) ^ e) * 8];
  const int ec = c & 7;
  const unsigned short* bfb0[4], * bfb1[4];
  #pragma unroll
  for (int s = 0; s < 4; ++s) {
    bfb0[s] = &sXB[0][c * 128 + ((4 * s +     h) ^ ec) * 8];
    bfb1[s] = &sXB[0][c * 128 + ((4 * s + 2 + h) ^ ec) * 8];
  }

  float16v zv;
  #pragma unroll
  for (int p = 0; p < 16; ++p) zv[p] = 0.f;
  float16v acc[2];
  acc[0] = zv; acc[1] = zv;
  float cs0 = 0.f, cs1 = 0.f;

  __syncthreads();

  #pragma unroll 2
  for (int t = 0; t < KTILES; ++t) {
    const int buf = t & 1;
    if (t + 1 < KTILES) {
      stage(buf ^ 1, xtp, xbpA, xbpB);
      xtp += KT * 64; xbpA += KT; xbpB += KT;
    }

    #pragma unroll
    for (int s = 0; s < 4; ++s) {
      short8 af[4];
      #pragma unroll
      for (int k = 0; k < 4; ++k)
        af[k] = *(const short8*)(afb[k] + buf * 8192 + s * 2048);

      float16v S = zv;
      #pragma unroll
      for (int k = 0; k < 4; ++k)
        S = __builtin_amdgcn_mfma_f32_32x32x16_bf16(af[k], qf[k], S, 0, 0, 0);

      unsigned q[8];
      #pragma unroll
      for (int g = 0; g < 8; ++g) {
        float w0 = __builtin_amdgcn_exp2f(S[2 * g]);
        float w1 = __builtin_amdgcn_exp2f(S[2 * g + 1]);
        unsigned u = pk2bf(w0, w1);
        q[g] = u;
        if (s & 1) cs1 = csum2(u, cs1); else cs0 = csum2(u, cs0);
      }

      union { unsigned d[4]; short8 s8; } a20, a21;
      a20.d[0] = q[0]; a20.d[1] = q[1]; a20.d[2] = q[2]; a20.d[3] = q[3];
      a21.d[0] = q[4]; a21.d[1] = q[5]; a21.d[2] = q[6]; a21.d[3] = q[7];

      short8 b20[2], b21[2];
      #pragma unroll
      for (int dt = 0; dt < 2; ++dt) {
        b20[dt] = *(const short8*)(bfb0[s] + buf * 8192 + dt * 4096);
        b21[dt] = *(const short8*)(bfb1[s] + buf * 8192 + dt * 4096);
      }
      #pragma unroll
      for (int dt = 0; dt < 2; ++dt)
        acc[dt] = __builtin_amdgcn_mfma_f32_32x32x16_bf16(a20.s8, b20[dt], acc[dt], 0, 0, 0);
      #pragma unroll
      for (int dt = 0; dt < 2; ++dt)
        acc[dt] = __builtin_amdgcn_mfma_f32_32x32x16_bf16(a21.s8, b21[dt], acc[dt], 0, 0, 0);
    }

    __syncthreads();
  }

  float cs = cs0 + cs1;

  union { float f; int i; } cu; cu.f = cs;
  cu.i = __builtin_amdgcn_ds_bpermute(bpaddr, cu.i);
  float cst = cs + cu.f;
  if (h == 0) pcs[(size_t)bx * 128 + wave * 32 + c] = cst;

  float* pw = pacc + (size_t)bx * (MTQ * 64);
  #pragma unroll
  for (int dt = 0; dt < 2; ++dt)
    #pragma unroll
    for (int p = 0; p < 16; ++p) {
      int m = wave * 32 + (p & 3) + 8 * (p >> 2) + 4 * h;
      pw[m * 64 + dt * 32 + c] = acc[dt][p];
    }
}

// ---------------------------------------------------------------------------
// flash_free (R20 EXPERIMENT): ZERO inter-wave coupling — the only structural
// family member never cleanly tested (R10 kept barriers; R13 was confounded
// by divergent loads). Each wave owns (32q x ALL KEYS_WG keys) with a
// wave-PRIVATE 16 KiB LDS double buffer (KTF=32-key tiles, 96 tiles); it
// self-synchronizes with per-wave counted vmcnt:
//   loop: s_waitcnt vmcnt(8)  [own stage(t) landed; stage(t+1) in flight]
//         -> compute tile t -> lgkmcnt(0) -> issue stage(t+2).
// NO s_barrier in the loop. Staging is 4x address-redundant (all 4 waves
// read the same keys; L2-hot) -> LDS-traffic floor ~41 µs.
// B-tile swizzle re-derived for 4-chunk rows: write gcB=(lane&3)^((lane>>2)&3),
// read ^(c&3) — max 2-way bank aliasing (free, m136). A-side/qf/σ-trick/
// epilogue identical to flash_kernel's s=0 path.
// Fork: barrier-coupling real -> 45-55 µs; per-wave latency floor -> ~73 µs.
// ---------------------------------------------------------------------------
__global__ void __launch_bounds__(256, 2) flash_free(
    const unsigned short* __restrict__ XT,
    const unsigned short* __restrict__ Xbf,
    float* __restrict__ pacc, float* __restrict__ pcs)
{
  const int bx   = blockIdx.x;
  const int ks   = bx % KS;
  const int mb   = (bx / KS) % MBF;
  const int b    = bx / (MBF * KS);
  const int tid  = threadIdx.x;
  const int wave = tid >> 6, lane = tid & 63;
  const int c = lane & 31, h = lane >> 5;
  const int cp = (c & 0x13) | ((c & 4) << 1) | ((c & 8) >> 1);  // swap bits 2,3
  const int m0 = mb * MTQ;
  const int bpaddr = (lane ^ 32) << 2;

  const unsigned short* XTb = XT  + (size_t)b * N_ * 64;
  const unsigned short* Xb  = Xbf + (size_t)b * 64 * N_;

  // wave-private tiles: [wave][buf][...]
  __shared__ __align__(16) unsigned short sT[4][2][KTF * 64];  // 32 KiB total
  __shared__ __align__(16) unsigned short sB[4][2][64 * KTF];  // 32 KiB total

  // --- qf loads FIRST (oldest in vmcnt FIFO; consumed before staging) ------
  short8 qf[4];
  #pragma unroll
  for (int k = 0; k < 4; ++k) {
    short8 raw = *(const short8*)(XTb +
        (size_t)(m0 + wave * 32 + c) * 64 + k * 16 + h * 8);
    unsigned o[4];
    const unsigned* rw = (const unsigned*)&raw;
    #pragma unroll
    for (int p4 = 0; p4 < 4; ++p4) {
      union { unsigned u; float f; } lo, hi;
      lo.u = rw[p4] << 16; hi.u = rw[p4] & 0xffff0000u;
      o[p4] = pk2bf(lo.f * C2, hi.f * C2);
    }
    qf[k] = *(const short8*)o;
  }
  __builtin_amdgcn_sched_barrier(0);   // qf issue+consume before DMA issue

  // --- DMA lane coords -----------------------------------------------------
  // A (sT): 8 rows x 8 chunks per dma16; row&7 == rr -> gcT = sc ^ rr.
  const int rr  = lane >> 3, sc = lane & 7;
  const int gcT = sc ^ rr;
  // B (sB): 16 rows x 4 chunks per dma16; row&3 = (lane>>2)&3 (batches of 16).
  const int gcB = (lane & 3) ^ ((lane >> 2) & 3);

  const int n0g0 = ks * KEYS_WG;

  const unsigned short* xtp = XTb + (size_t)(n0g0 + rr) * 64 + gcT * 8;
  const unsigned short* xbp = Xb  + (size_t)(lane >> 2) * N_ + n0g0 + gcB * 8;

  auto stageF = [&](int buf, const unsigned short* xt_, const unsigned short* xb_) {
    unsigned short* lt = &sT[wave][buf][0];
    unsigned short* lb = &sB[wave][buf][0];
    dma16(xt_,        lt,        lane);                // keys 0..7 of tile
    dma16(xt_ +  512, lt +  512, lane);                // 8..15
    dma16(xt_ + 1024, lt + 1024, lane);                // 16..23
    dma16(xt_ + 1536, lt + 1536, lane);                // 24..31
    dma16(xb_,                  lb,        lane);      // d rows  0..15
    dma16(xb_ + (size_t)16 * N_, lb +  512, lane);     // 16..31
    dma16(xb_ + (size_t)32 * N_, lb + 1024, lane);     // 32..47
    dma16(xb_ + (size_t)48 * N_, lb + 1536, lane);     // 48..63
  };

  stageF(0, xtp, xbp);  xtp += KTF * 64; xbp += KTF;   // tile 0
  stageF(1, xtp, xbp);  xtp += KTF * 64; xbp += KTF;   // tile 1

  // persistent per-lane LDS read bases (buf 0); buf -> +2048-elem offset
  const int e = cp & 7;
  const unsigned short* afbF[4];
  #pragma unroll
  for (int k = 0; k < 4; ++k)
    afbF[k] = &sT[wave][0][cp * 64 + ((2 * k + h) ^ e) * 8];
  const unsigned short* bfbF[2][2];   // [k2][dt]
  #pragma unroll
  for (int k2 = 0; k2 < 2; ++k2)
    #pragma unroll
    for (int dt = 0; dt < 2; ++dt)
      bfbF[k2][dt] = &sB[wave][0][(dt * 32 + c) * 32 + ((2 * k2 + h) ^ (c & 3)) * 8];

  float16v zv;
  #pragma unroll
  for (int p = 0; p < 16; ++p) zv[p] = 0.f;
  float16v acc[2];
  acc[0] = zv; acc[1] = zv;
  float cs0 = 0.f, cs1 = 0.f;

  auto computeF = [&](int buf, int par) {
    const int bo = buf * 2048;          // elements (4 KiB per buffer)
    short8 af[4];
    #pragma unroll
    for (int k = 0; k < 4; ++k)
      af[k] = *(const short8*)(afbF[k] + bo);

    float16v S = zv;
    #pragma unroll
    for (int k = 0; k < 4; ++k)
      S = __builtin_amdgcn_mfma_f32_32x32x16_bf16(af[k], qf[k], S, 0, 0, 0);

    unsigned q[8];
    #pragma unroll
    for (int g = 0; g < 8; ++g) {
      float w0 = __builtin_amdgcn_exp2f(S[2 * g]);
      float w1 = __builtin_amdgcn_exp2f(S[2 * g + 1]);
      unsigned u = pk2bf(w0, w1);
      q[g] = u;
      if (par) cs1 = csum2(u, cs1); else cs0 = csum2(u, cs0);
    }

    union { unsigned d[4]; short8 s8; } a20, a21;
    a20.d[0] = q[0]; a20.d[1] = q[1]; a20.d[2] = q[2]; a20.d[3] = q[3];
    a21.d[0] = q[4]; a21.d[1] = q[5]; a21.d[2] = q[6]; a21.d[3] = q[7];

    short8 bf0[2], bf1[2];
    #pragma unroll
    for (int dt = 0; dt < 2; ++dt) {
      bf0[dt] = *(const short8*)(bfbF[0][dt] + bo);
      bf1[dt] = *(const short8*)(bfbF[1][dt] + bo);
    }
    #pragma unroll
    for (int dt = 0; dt < 2; ++dt)
      acc[dt] = __builtin_amdgcn_mfma_f32_32x32x16_bf16(a20.s8, bf0[dt], acc[dt], 0, 0, 0);
    #pragma unroll
    for (int dt = 0; dt < 2; ++dt)
      acc[dt] = __builtin_amdgcn_mfma_f32_32x32x16_bf16(a21.s8, bf1[dt], acc[dt], 0, 0, 0);
  };

  // ---- barrier-free main loop: per-wave counted vmcnt pipeline ------------
  #pragma unroll 2
  for (int t = 0; t < NTF - 1; ++t) {
    asm volatile("s_waitcnt vmcnt(8)" ::: "memory");   // stage(t) landed
    __builtin_amdgcn_sched_barrier(0);
    computeF(t & 1, t & 1);
    asm volatile("s_waitcnt lgkmcnt(0)" ::: "memory"); // buf reads retired
    __builtin_amdgcn_sched_barrier(0);
    if (t + 2 < NTF) {                                 // overwrite buf (t&1)
      stageF(t & 1, xtp, xbp);
      xtp += KTF * 64; xbp += KTF;
    }
  }
  asm volatile("s_waitcnt vmcnt(0)" ::: "memory");     // last tile landed
  __builtin_amdgcn_sched_barrier(0);
  computeF((NTF - 1) & 1, (NTF - 1) & 1);

  float cs = cs0 + cs1;

  // -------- epilogue: wave-disjoint outputs (identical to control) ---------
  union { float f; int i; } cu; cu.f = cs;
  cu.i = __builtin_amdgcn_ds_bpermute(bpaddr, cu.i);
  float cst = cs + cu.f;
  if (h == 0) pcs[(size_t)bx * 128 + wave * 32 + c] = cst;

  float* pw = pacc + (size_t)bx * (MTQ * 64);
  #pragma unroll
  for (int dt = 0; dt < 2; ++dt)
    #pragma unroll
    for (int p = 0; p < 16; ++p) {
      int m = wave * 32 + (p & 3) + 8 * (p >> 2) + 4 * h;
      pw[m * 64 + dt * 32 + c] = acc[dt][p];
    }
}

// ---------------------------------------------------------------------------
// combine v2 (R18, kept) + R20 rider: final iteration (t==ITERS-1) skips the
// dead Xbf/XT writes (never read — no flash follows) and pass 3 entirely.
// ---------------------------------------------------------------------------
__global__ void combine_kernel(const float* __restrict__ pacc,
                               const float* __restrict__ pcs,
                               float* __restrict__ out,
                               unsigned short* __restrict__ XT,
                               unsigned short* __restrict__ Xbf, int t)
{
  const int bx  = blockIdx.x;
  const int dh  = bx & 1;
  const int q32 = (bx >> 1) % 288, b = bx / 576;
  const int m0  = q32 * 32;
  const int fb  = q32 >> 2, sub = q32 & 3;
  const int base = (b * MBF + fb) * KS;
  const int tid = threadIdx.x;
  const bool last = (t == ITERS - 1);
  __shared__ float accs[32 * 33];
  __shared__ float cstl[32];

  float2 xc[2];
  int   dl2[2], ml2[2];
  size_t ob2[2];
  #pragma unroll
  for (int r = 0; r < 2; ++r) {
    int idx = r * 256 + tid;
    int ml = (idx & 15) * 2, dl = idx >> 4;
    int d  = dh * 32 + dl;
    size_t obase = (((size_t)b * 5 + t) * 64 + d) * N_ + m0 + ml;
    xc[r] = *(const float2*)(out + obase);
    ml2[r] = ml; dl2[r] = dl; ob2[r] = obase;
  }

  {
    int ml = tid >> 3, f4 = tid & 7;
    size_t off = (size_t)(sub * 32 + ml) * 64 + dh * 32 + f4 * 4;
    float4 s = make_float4(0.f, 0.f, 0.f, 0.f);
    #pragma unroll
    for (int k = 0; k < KS; ++k) {
      float4 v = *(const float4*)(pacc + (size_t)(base + k) * 8192 + off);
      s.x += v.x; s.y += v.y; s.z += v.z; s.w += v.w;
    }
    float* a = &accs[ml * 33 + f4 * 4];
    a[0] = s.x; a[1] = s.y; a[2] = s.z; a[3] = s.w;
  }
  if (tid < 32) {
    float cv = 0.f;
    #pragma unroll
    for (int k = 0; k < KS; ++k) cv += pcs[(size_t)(base + k) * 128 + sub * 32 + tid];
    cstl[tid] = cv;
  }
  __syncthreads();

  #pragma unroll
  for (int r = 0; r < 2; ++r) {
    int ml = ml2[r], dl = dl2[r];
    float a0 = accs[ml * 33 + dl], a1 = accs[(ml + 1) * 33 + dl];
    float v0 = STEP * (a0 / cstl[ml])     + (1.f - STEP) * xc[r].x;
    float v1 = STEP * (a1 / cstl[ml + 1]) + (1.f - STEP) * xc[r].y;
    *(float2*)(out + ob2[r] + (size_t)64 * N_) = make_float2(v0, v1);  // slice t+1
    if (!last) {
      int d = dh * 32 + dl;
      *(unsigned*)(Xbf + ((size_t)b * 64 + d) * N_ + m0 + ml) = pk2bf(v0, v1);
      accs[ml * 33 + dl] = v0; accs[(ml + 1) * 33 + dl] = v1;  // for transpose
    }
  }
  if (last) return;
  __syncthreads();

  #pragma unroll
  for (int r = 0; r < 2; ++r) {
    int idx = r * 256 + tid;
    int m = idx >> 4, dl = (idx & 15) * 2;
    *(unsigned*)(XT + ((size_t)b * N_ + m0 + m) * 64 + dh * 32 + dl)
        = pk2bf(accs[m * 33 + dl], accs[m * 33 + dl + 1]);
  }
}

// ---------------------------------------------------------------------------
extern "C" void kernel_launch(void* const* d_in, const int* in_sizes, int n_in,
                              void* d_out, int out_size, void* d_ws, size_t ws_size,
                              hipStream_t stream)
{
  (void)in_sizes; (void)n_in; (void)out_size; (void)ws_size;
  const float* xin = (const float*)d_in[0];
  float* out = (float*)d_out;
  char* ws = (char*)d_ws;

  // workspace layout (19,095,552 B used):
  unsigned short* XT  = (unsigned short*)(ws);             //  2,359,296 B
  unsigned short* Xbf = (unsigned short*)(ws +  2359296);  //  2,359,296 B
  float*          pacc = (float*)(ws +  4718592);          // 14,155,776 B (432*8192*4)
  float*          pcs  = (float*)(ws + 18874368);          //    221,184 B (432*128*4)

  prep_kernel<<<B_ * PB2, 256, 0, stream>>>(xin, out, XT, Xbf);
  for (int t = 0; t < ITERS; ++t) {
    if (t & 1) flash_free  <<<NWG, 256, 0, stream>>>(XT, Xbf, pacc, pcs);
    else       flash_kernel<<<NWG, 256, 0, stream>>>(XT, Xbf, pacc, pcs);
    combine_kernel<<<CGRID, 256, 0, stream>>>(pacc, pcs, out, XT, Xbf, t);
  }
}

// Round 16
// 336.686 us; speedup vs baseline: 1.0790x; 1.0790x over previous
//
#include <hip/hip_runtime.h>
#include <hip/hip_bf16.h>

// Problem constants (B=2, D=64, H=W=96)
constexpr int B_    = 2;
constexpr int N_    = 9216;      // 96*96
constexpr int ITERS = 4;

constexpr int MTQ     = 128;          // queries per workgroup (m-split: 32/wave)
constexpr int MBF     = N_ / MTQ;     // 72 m-blocks
constexpr int KS      = 3;            // key-split factor
constexpr int KEYS_WG = N_ / KS;      // 3072 keys per workgroup
constexpr int KT      = 128;          // keys per staged tile
constexpr int KTILES  = KEYS_WG / KT; // 24 tiles -> 24 barriers
constexpr int NWG     = B_ * MBF * KS;// 432 flash workgroups — all <= cap 2/CU
constexpr int PB2     = 288;          // prep n-blocks of 32
constexpr int CGRID   = B_ * (N_ / 32) * 2; // 1152 combine workgroups

constexpr float STEP = 0.5f;
constexpr float C2   = 0.43280851226668905f;  // KBW * log2(e)

using short8   = __attribute__((ext_vector_type(8))) short;
using float16v = __attribute__((ext_vector_type(16))) float;
typedef __attribute__((ext_vector_type(2))) __bf16 bf16x2;

__device__ __forceinline__ unsigned short f2bf(float f) {
  union { float f; unsigned u; } v; v.f = f;
  unsigned u = v.u;
  unsigned r = (u + 0x7fffu + ((u >> 16) & 1u)) >> 16;   // RNE
  return (unsigned short)r;
}

#if __has_builtin(__builtin_amdgcn_cvt_pk_bf16_f32)
__device__ __forceinline__ unsigned pk2bf(float a, float b) {
  bf16x2 r = __builtin_amdgcn_cvt_pk_bf16_f32(a, b);   // low <- a, high <- b, RNE
  union { bf16x2 h; unsigned u; } v; v.h = r; return v.u;
}
#else
__device__ __forceinline__ unsigned pk2bf(float a, float b) {
  return (unsigned)f2bf(a) | ((unsigned)f2bf(b) << 16);
}
#endif

// cs += lo(u) + hi(u) where u is a packed bf16 pair — 1 instr via dot2.
__device__ __forceinline__ float csum2(unsigned u, float cs) {
#if __has_builtin(__builtin_amdgcn_fdot2_f32_bf16)
  union { unsigned x; bf16x2 h; } a, o;
  a.x = u; o.x = 0x3f803f80u;                          // (1.0, 1.0) bf16
  return __builtin_amdgcn_fdot2_f32_bf16(a.h, o.h, cs, false);
#else
  union { unsigned u; float f; } lo, hi;
  lo.u = u << 16; hi.u = u & 0xffff0000u;
  return cs + lo.f + hi.f;
#endif
}

// Async global->LDS DMA, 16 B/lane; lds_base wave-uniform, lane i -> base+16i.
__device__ __forceinline__ void dma16(const unsigned short* g,
                                      unsigned short* lds_base, int lane) {
#if __has_builtin(__builtin_amdgcn_global_load_lds)
  __builtin_amdgcn_global_load_lds(
      (const __attribute__((address_space(1))) unsigned int*)g,
      (__attribute__((address_space(3))) unsigned int*)lds_base, 16, 0, 0);
#else
  *(int4*)((char*)lds_base + lane * 16) = *(const int4*)g;
#endif
}

// ---------------------------------------------------------------------------
// prep v2 (R19, best measured ~4.5 µs): 576 blocks (32 n-cols x 64 d), float2
// loads, packed 32-bit bf16 stores, LDS [64][33] (2-way alias max, free).
// ---------------------------------------------------------------------------
__global__ void prep_kernel(const float* __restrict__ xin, float* __restrict__ out,
                            unsigned short* __restrict__ XT,
                            unsigned short* __restrict__ Xbf)
{
  const int bx = blockIdx.x;
  const int nb = bx % PB2, b = bx / PB2;
  const int n0 = nb * 32;
  const int tid = threadIdx.x;
  __shared__ float tile[64 * 33];

  #pragma unroll
  for (int r = 0; r < 4; ++r) {
    int idx = r * 256 + tid;                 // 0..1023 = 64 d x 16 j-pairs
    int d = idx >> 4, j2 = (idx & 15) * 2;
    size_t gsrc = ((size_t)b * 64 + d) * N_ + n0 + j2;
    float2 v = *(const float2*)(xin + gsrc);
    *(float2*)(out + (((size_t)b * 5 + 0) * 64 + d) * N_ + n0 + j2) = v;
    *(unsigned*)(Xbf + gsrc) = pk2bf(v.x, v.y);
    tile[d * 33 + j2]     = v.x;
    tile[d * 33 + j2 + 1] = v.y;
  }
  __syncthreads();

  #pragma unroll
  for (int r = 0; r < 4; ++r) {
    int idx = r * 256 + tid;                 // 0..1023 = 32 n x 32 d-pairs
    int nl = idx >> 5, d2 = (idx & 31) * 2;
    *(unsigned*)(XT + ((size_t)b * N_ + n0 + nl) * 64 + d2)
        = pk2bf(tile[d2 * 33 + nl], tile[(d2 + 1) * 33 + nl]);
  }
}

// ---------------------------------------------------------------------------
// flash (R17 config, FINAL — 72.6-75.0 µs across R17-R20 runs; best of 14
// structural variants). Session conclusion on the flash bound:
//   * Per-wave dependency-latency floor: ~1.1k cy per 32qx32k unit, 162
//     units/SIMD fixed by algorithm FLOPs -> ~73 µs.
//   * Evidence: R12 (2x occupancy -> per-wave 2x slower, wall unchanged),
//     R20 (zero inter-wave coupling, per-wave vmcnt pipeline -> 18% SLOWER:
//     86 µs — barriers were never the cost; shared staging helps),
//     plus nulls for staging depth, counted vmcnt, setprio, W-carry
//     (compiler-defeated twice), LDS-read halving, barrier count.
//   * The QK(4-dep MFMA) -> exp2/pack (serial VALU) -> PV chain is the
//     algorithmic critical path; CU latency-hiding for this mix saturates
//     at ~2 waves/SIMD. σ-trick already removed all cross-lane moves.
// KT=128/KS=3: 24 barriers, 432 blocks (cap 2/CU, single residency round).
// σ-trick (R6): af reads key row σ(c)=c with bits 2<->3 swapped -> W lands
// A-operand-ordered. Queries pre-scaled by C2 -> w = exp2(S). Colsum via
// bf16 dot2 on ROUNDED weights (matches reference bf16 numerics).
// ---------------------------------------------------------------------------
__global__ void __launch_bounds__(256, 2) flash_kernel(
    const unsigned short* __restrict__ XT,
    const unsigned short* __restrict__ Xbf,
    float* __restrict__ pacc, float* __restrict__ pcs)
{
  const int bx   = blockIdx.x;
  const int ks   = bx % KS;
  const int mb   = (bx / KS) % MBF;
  const int b    = bx / (MBF * KS);
  const int tid  = threadIdx.x;
  const int wave = tid >> 6, lane = tid & 63;
  const int c = lane & 31, h = lane >> 5;
  const int cp = (c & 0x13) | ((c & 4) << 1) | ((c & 8) >> 1);  // swap bits 2,3
  const int m0 = mb * MTQ;
  const int bpaddr = (lane ^ 32) << 2;      // ds_bpermute byte index (epilogue)

  const unsigned short* XTb = XT  + (size_t)b * N_ * 64;
  const unsigned short* Xb  = Xbf + (size_t)b * 64 * N_;

  __shared__ __align__(16) unsigned short sXT[2][KT * 64];   // [key][d] 16KiB x2
  __shared__ __align__(16) unsigned short sXB[2][64 * KT];   // [d][n]   16KiB x2

  // sXT: 8 rows x 8 chunks per dma16; row&7 == rr -> lane-constant swizzle.
  const int rr  = lane >> 3, sc = lane & 7;
  const int gcT = sc ^ rr;
  // sXB: 4 rows x 16 chunks per dma16; row&7 = (j&1)*4 + rr4 -> two swizzles.
  const int rr4 = lane >> 4, sc16 = lane & 15;
  const int gcB0 = sc16 ^ rr4;                  // j even
  const int gcB1 = sc16 ^ (4 + rr4);            // j odd

  const int n0g0 = ks * KEYS_WG;

  const unsigned short* xtp  = XTb + (size_t)(n0g0 + wave * 32 + rr) * 64 + gcT * 8;
  const unsigned short* xbpA = Xb  + (size_t)(wave * 16 + rr4) * N_ + n0g0 + gcB0 * 8;
  const unsigned short* xbpB = Xb  + (size_t)(wave * 16 + rr4) * N_ + n0g0 + gcB1 * 8;

  auto stage = [&](int buf, const unsigned short* xt_,
                   const unsigned short* xbA_, const unsigned short* xbB_) {
    unsigned short* lt = &sXT[buf][wave * 32 * 64];    // 32 key rows / wave
    unsigned short* lb = &sXB[buf][wave * 16 * 128];   // 16 d rows / wave
    dma16(xt_,        lt,        lane);
    dma16(xt_ +  512, lt +  512, lane);
    dma16(xt_ + 1024, lt + 1024, lane);
    dma16(xt_ + 1536, lt + 1536, lane);
    dma16(xbA_,                    lb,        lane);
    dma16(xbB_ + (size_t) 4 * N_,  lb +  512, lane);
    dma16(xbA_ + (size_t) 8 * N_,  lb + 1024, lane);
    dma16(xbB_ + (size_t)12 * N_,  lb + 1536, lane);
  };

  stage(0, xtp, xbpA, xbpB);                 // prologue DMA flies under qf setup
  xtp += KT * 64; xbpA += KT; xbpB += KT;

  // wave's resident query fragments (B-operand), pre-scaled by C2
  short8 qf[4];
  #pragma unroll
  for (int k = 0; k < 4; ++k) {
    short8 raw = *(const short8*)(XTb +
        (size_t)(m0 + wave * 32 + c) * 64 + k * 16 + h * 8);
    unsigned o[4];
    const unsigned* rw = (const unsigned*)&raw;
    #pragma unroll
    for (int p4 = 0; p4 < 4; ++p4) {
      union { unsigned u; float f; } lo, hi;
      lo.u = rw[p4] << 16; hi.u = rw[p4] & 0xffff0000u;
      o[p4] = pk2bf(lo.f * C2, hi.f * C2);
    }
    qf[k] = *(const short8*)o;
  }

  const int e = cp & 7;
  const unsigned short* afb[4];
  #pragma unroll
  for (int k = 0; k < 4; ++k)
    afb[k] = &sXT[0][cp * 64 + ((2 * k + h) ^ e) * 8];
  const int ec = c & 7;
  const unsigned short* bfb0[4], * bfb1[4];   // [s], k2=0 / k2=1
  #pragma unroll
  for (int s = 0; s < 4; ++s) {
    bfb0[s] = &sXB[0][c * 128 + ((4 * s +     h) ^ ec) * 8];
    bfb1[s] = &sXB[0][c * 128 + ((4 * s + 2 + h) ^ ec) * 8];
  }

  float16v zv;
  #pragma unroll
  for (int p = 0; p < 16; ++p) zv[p] = 0.f;
  float16v acc[2];
  acc[0] = zv; acc[1] = zv;
  float cs0 = 0.f, cs1 = 0.f;

  __syncthreads();               // buf0 ready (drains prologue DMA + qf loads)

  #pragma unroll 2
  for (int t = 0; t < KTILES; ++t) {
    const int buf = t & 1;       // constexpr after unroll-2
    if (t + 1 < KTILES) {        // prefetch next tile FIRST (overlaps compute)
      stage(buf ^ 1, xtp, xbpA, xbpB);
      xtp += KT * 64; xbpA += KT; xbpB += KT;
    }

    #pragma unroll
    for (int s = 0; s < 4; ++s) {           // 4 key subtiles of 32
      short8 af[4];
      #pragma unroll
      for (int k = 0; k < 4; ++k)
        af[k] = *(const short8*)(afb[k] + buf * 8192 + s * 2048);

      float16v S = zv;
      #pragma unroll
      for (int k = 0; k < 4; ++k)
        S = __builtin_amdgcn_mfma_f32_32x32x16_bf16(af[k], qf[k], S, 0, 0, 0);

      unsigned q[8];
      #pragma unroll
      for (int g = 0; g < 8; ++g) {
        float w0 = __builtin_amdgcn_exp2f(S[2 * g]);
        float w1 = __builtin_amdgcn_exp2f(S[2 * g + 1]);
        unsigned u = pk2bf(w0, w1);
        q[g] = u;
        if (s & 1) cs1 = csum2(u, cs1); else cs0 = csum2(u, cs0);
      }

      union { unsigned d[4]; short8 s8; } a20, a21;
      a20.d[0] = q[0]; a20.d[1] = q[1]; a20.d[2] = q[2]; a20.d[3] = q[3];
      a21.d[0] = q[4]; a21.d[1] = q[5]; a21.d[2] = q[6]; a21.d[3] = q[7];

      short8 b20[2], b21[2];
      #pragma unroll
      for (int dt = 0; dt < 2; ++dt) {
        b20[dt] = *(const short8*)(bfb0[s] + buf * 8192 + dt * 4096);
        b21[dt] = *(const short8*)(bfb1[s] + buf * 8192 + dt * 4096);
      }
      #pragma unroll
      for (int dt = 0; dt < 2; ++dt)
        acc[dt] = __builtin_amdgcn_mfma_f32_32x32x16_bf16(a20.s8, b20[dt], acc[dt], 0, 0, 0);
      #pragma unroll
      for (int dt = 0; dt < 2; ++dt)
        acc[dt] = __builtin_amdgcn_mfma_f32_32x32x16_bf16(a21.s8, b21[dt], acc[dt], 0, 0, 0);
    }

    __syncthreads();   // all waves done with buf; prefetch DMA drained
  }

  float cs = cs0 + cs1;

  // -------- epilogue: wave-disjoint outputs, direct global writes ----------
  union { float f; int i; } cu; cu.f = cs;
  cu.i = __builtin_amdgcn_ds_bpermute(bpaddr, cu.i);
  float cst = cs + cu.f;                     // both h-halves hold the total
  if (h == 0) pcs[(size_t)bx * 128 + wave * 32 + c] = cst;

  float* pw = pacc + (size_t)bx * (MTQ * 64);
  #pragma unroll
  for (int dt = 0; dt < 2; ++dt)
    #pragma unroll
    for (int p = 0; p < 16; ++p) {
      int m = wave * 32 + (p & 3) + 8 * (p >> 2) + 4 * h;
      pw[m * 64 + dt * 32 + c] = acc[dt][p];
    }
}

// ---------------------------------------------------------------------------
// combine v2 (R18) + last-iter rider (R20, verified correct): t==ITERS-1
// skips the dead Xbf/XT writes (no flash follows) and pass 3 entirely.
// ~7.5-8 µs/iter (near the ~6 µs BW floor).
// ---------------------------------------------------------------------------
__global__ void combine_kernel(const float* __restrict__ pacc,
                               const float* __restrict__ pcs,
                               float* __restrict__ out,
                               unsigned short* __restrict__ XT,
                               unsigned short* __restrict__ Xbf, int t)
{
  const int bx  = blockIdx.x;
  const int dh  = bx & 1;                        // d-half
  const int q32 = (bx >> 1) % 288, b = bx / 576;
  const int m0  = q32 * 32;
  const int fb  = q32 >> 2, sub = q32 & 3;
  const int base = (b * MBF + fb) * KS;
  const int tid = threadIdx.x;
  const bool last = (t == ITERS - 1);
  __shared__ float accs[32 * 33];
  __shared__ float cstl[32];

  // prefetch xc (out slice t) before the barrier
  float2 xc[2];
  int   dl2[2], ml2[2];
  size_t ob2[2];
  #pragma unroll
  for (int r = 0; r < 2; ++r) {
    int idx = r * 256 + tid;
    int ml = (idx & 15) * 2, dl = idx >> 4;
    int d  = dh * 32 + dl;
    size_t obase = (((size_t)b * 5 + t) * 64 + d) * N_ + m0 + ml;
    xc[r] = *(const float2*)(out + obase);
    ml2[r] = ml; dl2[r] = dl; ob2[r] = obase;
  }

  // pass 1: sum KS pacc partials
  {
    int ml = tid >> 3, f4 = tid & 7;
    size_t off = (size_t)(sub * 32 + ml) * 64 + dh * 32 + f4 * 4;
    float4 s = make_float4(0.f, 0.f, 0.f, 0.f);
    #pragma unroll
    for (int k = 0; k < KS; ++k) {
      float4 v = *(const float4*)(pacc + (size_t)(base + k) * 8192 + off);
      s.x += v.x; s.y += v.y; s.z += v.z; s.w += v.w;
    }
    float* a = &accs[ml * 33 + f4 * 4];
    a[0] = s.x; a[1] = s.y; a[2] = s.z; a[3] = s.w;
  }
  if (tid < 32) {
    float cv = 0.f;
    #pragma unroll
    for (int k = 0; k < KS; ++k) cv += pcs[(size_t)(base + k) * 128 + sub * 32 + tid];
    cstl[tid] = cv;
  }
  __syncthreads();

  // pass 2: normalize, blend, write out slice t+1 (+ Xbf unless last)
  #pragma unroll
  for (int r = 0; r < 2; ++r) {
    int ml = ml2[r], dl = dl2[r];
    float a0 = accs[ml * 33 + dl], a1 = accs[(ml + 1) * 33 + dl];
    float v0 = STEP * (a0 / cstl[ml])     + (1.f - STEP) * xc[r].x;
    float v1 = STEP * (a1 / cstl[ml + 1]) + (1.f - STEP) * xc[r].y;
    *(float2*)(out + ob2[r] + (size_t)64 * N_) = make_float2(v0, v1);
    if (!last) {
      int d = dh * 32 + dl;
      *(unsigned*)(Xbf + ((size_t)b * 64 + d) * N_ + m0 + ml) = pk2bf(v0, v1);
      accs[ml * 33 + dl] = v0; accs[(ml + 1) * 33 + dl] = v1;
    }
  }
  if (last) return;
  __syncthreads();

  // pass 3: transposed XT write
  #pragma unroll
  for (int r = 0; r < 2; ++r) {
    int idx = r * 256 + tid;
    int m = idx >> 4, dl = (idx & 15) * 2;
    *(unsigned*)(XT + ((size_t)b * N_ + m0 + m) * 64 + dh * 32 + dl)
        = pk2bf(accs[m * 33 + dl], accs[m * 33 + dl + 1]);
  }
}

// ---------------------------------------------------------------------------
extern "C" void kernel_launch(void* const* d_in, const int* in_sizes, int n_in,
                              void* d_out, int out_size, void* d_ws, size_t ws_size,
                              hipStream_t stream)
{
  (void)in_sizes; (void)n_in; (void)out_size; (void)ws_size;
  const float* xin = (const float*)d_in[0];
  float* out = (float*)d_out;
  char* ws = (char*)d_ws;

  // workspace layout (19,095,552 B used):
  unsigned short* XT  = (unsigned short*)(ws);             //  2,359,296 B
  unsigned short* Xbf = (unsigned short*)(ws +  2359296);  //  2,359,296 B
  float*          pacc = (float*)(ws +  4718592);          // 14,155,776 B (432*8192*4)
  float*          pcs  = (float*)(ws + 18874368);          //    221,184 B (432*128*4)

  prep_kernel<<<B_ * PB2, 256, 0, stream>>>(xin, out, XT, Xbf);
  for (int t = 0; t < ITERS; ++t) {
    flash_kernel<<<NWG, 256, 0, stream>>>(XT, Xbf, pacc, pcs);
    combine_kernel<<<CGRID, 256, 0, stream>>>(pacc, pcs, out, XT, Xbf, t);
  }
}